// Round 4
// baseline (9218.633 us; speedup 1.0000x reference)
//
#include <hip/hip_runtime.h>

#define TSEQ 2048
#define NB   20
#define NIN  256
#define NH   512
#define NOUT 128

typedef unsigned int   u32;
typedef unsigned short u16;
typedef _Float16 f16x2 __attribute__((ext_vector_type(2)));

// dynamic LDS layout
#define SM_W     0                 // 131072 B: WLw uint4[16][512] (recurrence) / WL uint2[32][512] (pre1)
#define SM_HX    131072            // 1024 B: h exchange, sigma-swizzled f16[512]
#define SM_INP   (131072 + 1024)   // 2048 B: u32 [2][256] input staging (pre roles)
#define SMEM_BYTES (131072 + 1024 + 2048)

__device__ __forceinline__ u32 packh2(float a, float b) {
  f16x2 p; p.x = (_Float16)a; p.y = (_Float16)b;
  return __builtin_bit_cast(u32, p);
}

__device__ __forceinline__ float dot2(u32 w, u32 h, float acc) {
  return __builtin_amdgcn_fdot2(__builtin_bit_cast(f16x2, w),
                                __builtin_bit_cast(f16x2, h), acc, false);
}

__device__ __forceinline__ int acq(const int* p) {
  return __hip_atomic_load(p, __ATOMIC_ACQUIRE, __HIP_MEMORY_SCOPE_AGENT);
}
__device__ __forceinline__ void rel(int* p, int v) {
  __hip_atomic_store(p, v, __ATOMIC_RELEASE, __HIP_MEMORY_SCOPE_AGENT);
}

// cross-lane add via DPP (VALU pipe, no LDS). CTRL: 0x140 row_mirror (xor15),
// 0x141 row_half_mirror (xor7), 0x4E quad[2,3,0,1] (xor2), 0xB1 quad[1,0,3,2] (xor1)
template<int CTRL>
__device__ __forceinline__ float dpp_add(float x) {
  int v = __builtin_amdgcn_update_dpp(0, __builtin_bit_cast(int, x), CTRL, 0xF, 0xF, true);
  return x + __builtin_bit_cast(float, v);
}

template<int CTRL>
__device__ __forceinline__ u32 dpp_mov_u32(u32 x) {
  return (u32)__builtin_amdgcn_update_dpp(0, (int)x, CTRL, 0xF, 0xF, true);
}

__device__ __forceinline__ float fast_tanh(float x) {
  float xc = fminf(fmaxf(x, -15.f), 15.f);
  float e = __builtin_amdgcn_exp2f(xc * 2.8853900817779268f);  // exp(2x)
  return (e - 1.f) * __builtin_amdgcn_rcpf(e + 1.f);
}

// sigma-swizzle for hx: granule G (16B) -> physical byte offset.
// G = 4*g + c (g = h-index>>5 = lam, c = chunk). phys = 64*pi(g) + 16*(c ^ (g&3)),
// pi(g) = g ^ (g>>2). Reader banks: 16*(pi&1) + 4*(c^(g&3)) -> 8 banks x 2-way = free.
__device__ __forceinline__ int hx_gran_off(int g, int c) {
  int pg = (g ^ (g >> 2)) & 15;
  return 64 * pg + 16 * (c ^ (g & 3));
}

// Persistent fused pipeline. grid = 160 blocks x 512 threads, 1 block/CU.
//  bid   0..39 : pre0 (b=bid>>1, half=bid&1)        pre0 = x@Wih0^T + bih0 (f16)
//  bid  40..59 : L0 recurrence (b=bid-40)           out0 = h packed f16 pairs
//  bid 60..139 : pre1 (b=(bid-60)>>2, sub=(bid-60)&3) 4-way t-chunked gather
//  bid140..159 : L1 recurrence (b=bid-140)          h1f = last h (f32)
__global__ __launch_bounds__(512, 2) void rnn_persist(
    const float* __restrict__ x,    const float* __restrict__ h0,
    const float* __restrict__ Wih0, const float* __restrict__ Whh0,
    const float* __restrict__ bih0, const float* __restrict__ bhh0,
    const float* __restrict__ Wih1, const float* __restrict__ Whh1,
    const float* __restrict__ bih1, const float* __restrict__ bhh1,
    u16* __restrict__ pre0, u32* __restrict__ out0,
    u16* __restrict__ pre1, float* __restrict__ h1f,
    int* __restrict__ flags)
{
  extern __shared__ char smem[];
  const int tid = threadIdx.x;
  const int bid = blockIdx.x;

  if (bid < 40) {
    // ---------------- pre0: x @ Wih0^T + bih0 (verified round 1/2) ----------------
    u32* inp = (u32*)(smem + SM_INP);
    const int b = bid >> 1, half = bid & 1, t0 = half * 1024;
    const int n = tid;
    u32 wr[128];
    const float4* W4 = (const float4*)(Wih0 + (size_t)n * NIN);
#pragma unroll
    for (int j = 0; j < 64; j++) {
      float4 w = W4[j];
      wr[2*j] = packh2(w.x, w.y); wr[2*j+1] = packh2(w.z, w.w);
    }
    const float bias = bih0[n];
    const float* xb = x + ((size_t)b * TSEQ + t0) * NIN;
    u16* op = pre0 + ((size_t)b * TSEQ + t0) * NH;

    float2 r = make_float2(0.f, 0.f);
    if (tid < 128) r = ((const float2*)xb)[tid];
    int cur = 0;
    for (int t = 0; t < 1024; t++) {
      if (tid < 128) inp[cur * 256 + tid] = packh2(r.x, r.y);
      __syncthreads();
      if (t + 1 < 1024 && tid < 128)
        r = ((const float2*)(xb + (size_t)(t + 1) * NIN))[tid];
      float a0 = bias, a1 = 0.f;
      const uint4* xp = (const uint4*)(inp + cur * 256);
#pragma unroll
      for (int j = 0; j < 32; j++) {
        uint4 hv = xp[j];
        a0 = dot2(wr[4*j+0], hv.x, a0); a1 = dot2(wr[4*j+1], hv.y, a1);
        a0 = dot2(wr[4*j+2], hv.z, a0); a1 = dot2(wr[4*j+3], hv.w, a1);
      }
      op[(size_t)t * NH + n] = __builtin_bit_cast(u16, (_Float16)(a0 + a1));
      cur ^= 1;
      if (((t + 1) & 7) == 0) {
        __syncthreads();
        if (tid == 0) rel(flags + bid * 32, t + 1);
      }
    }
    return;
  }

  if (bid >= 60 && bid < 140) {
    // ---------------- pre1: out0 @ Wih1^T + bih1, 4-way t-chunk split ----------------
    uint2* WL  = (uint2*)(smem + SM_W);
    u32*   inp = (u32*)(smem + SM_INP);
    const int b = (bid - 60) >> 2, sub = (bid - 60) & 3;
    const int n = tid;
    u32 wr[192];
    const float4* W4 = (const float4*)(Wih1 + (size_t)n * NH);
#pragma unroll
    for (int j = 0; j < 96; j++) {
      float4 w = W4[j];
      wr[2*j] = packh2(w.x, w.y); wr[2*j+1] = packh2(w.z, w.w);
    }
#pragma unroll
    for (int j2 = 0; j2 < 32; j2++) {
      float4 w = W4[96 + j2];
      WL[j2 * NH + n] = make_uint2(packh2(w.x, w.y), packh2(w.z, w.w));
    }
    const float bias = bih1[n];
    __syncthreads();

    const u32* ip = out0 + (size_t)b * TSEQ * 256;
    u16* op = pre1 + (size_t)b * TSEQ * NH;
    const int* flagOut0 = flags + (40 + b) * 32;
    int* flagMy = flags + (60 + b * 4 + sub) * 32;
    int seen = 0, cur = 0;
#pragma unroll 1
    for (int c = sub; c < TSEQ / 8; c += 4) {
      const int tbase = c * 8;
      while (seen < tbase + 8) seen = acq(flagOut0);
      u32 rin = (tid < 256) ? ip[(size_t)tbase * 256 + tid] : 0;
#pragma unroll 1
      for (int qq = 0; qq < 8; qq++) {
        const int t = tbase + qq;
        if (tid < 256) inp[cur * 256 + tid] = rin;
        __syncthreads();
        if (qq + 1 < 8 && tid < 256) rin = ip[(size_t)(t + 1) * 256 + tid];
        float a0 = bias, a1 = 0.f;
        const uint4* hp4 = (const uint4*)(inp + cur * 256);
#pragma unroll
        for (int j = 0; j < 48; j++) {
          uint4 hv = hp4[j];
          a0 = dot2(wr[4*j+0], hv.x, a0); a1 = dot2(wr[4*j+1], hv.y, a1);
          a0 = dot2(wr[4*j+2], hv.z, a0); a1 = dot2(wr[4*j+3], hv.w, a1);
        }
#pragma unroll
        for (int jj = 0; jj < 16; jj++) {
          uint4 hv = hp4[48 + jj];
          uint2 w0 = WL[(2*jj)   * NH + n];
          uint2 w1 = WL[(2*jj+1) * NH + n];
          a0 = dot2(w0.x, hv.x, a0); a1 = dot2(w0.y, hv.y, a1);
          a0 = dot2(w1.x, hv.z, a0); a1 = dot2(w1.y, hv.w, a1);
        }
        op[(size_t)t * NH + n] = __builtin_bit_cast(u16, (_Float16)(a0 + a1));
        cur ^= 1;
      }
      __syncthreads();
      if (tid == 0) rel(flagMy, tbase + 8);
    }
    return;
  }

  // ---------------- L0 / L1 recurrence: scatter + 16-lane DPP butterfly ----------------
  const bool isL0 = (bid < 60);
  const int b = isL0 ? (bid - 40) : (bid - 140);
  const float* Wg = isL0 ? Whh0 : Whh1;
  const float* bp = isL0 ? bhh0 : bhh1;

  uint4* WLw4 = (uint4*)(smem + SM_W);  // slot s at (s*512 + tid), s = 0..15
  char*  hxc  = smem + SM_HX;           // sigma-swizzled f16[512]

  const int lam = tid & 15;             // k-group: k in [32*lam, 32*lam+32)
  const int ns  = tid >> 4;             // n-slice: rows 16*ns .. 16*ns+15

  // Weights rows 0..11 -> registers (fully static indices; AGPR-backed is fine)
  u32 wj[12][16];
#pragma unroll
  for (int j = 0; j < 12; j++) {
    const float4* Wr = (const float4*)(Wg + (size_t)(16 * ns + j) * NH + 32 * lam);
#pragma unroll
    for (int k4 = 0; k4 < 8; k4++) {
      float4 w = Wr[k4];
      wj[j][2*k4] = packh2(w.x, w.y); wj[j][2*k4+1] = packh2(w.z, w.w);
    }
  }
  // Weights rows 12..15 -> LDS. Slot s = (j-12)*4 + q holds col-u32s [4q..4q+3].
#pragma unroll
  for (int j = 12; j < 16; j++) {
    const float4* Wr = (const float4*)(Wg + (size_t)(16 * ns + j) * NH + 32 * lam);
#pragma unroll
    for (int q = 0; q < 4; q++) {
      float4 wA = Wr[2*q], wB = Wr[2*q+1];
      WLw4[((j - 12) * 4 + q) * 512 + tid] =
          make_uint4(packh2(wA.x, wA.y), packh2(wA.z, wA.w),
                     packh2(wB.x, wB.y), packh2(wB.z, wB.w));
    }
  }
  const float bias = bp[tid];           // final owner n == tid

  // precomputed hx addresses (loop-invariant)
  int hadr[4];
#pragma unroll
  for (int c = 0; c < 4; c++) hadr[c] = hx_gran_off(lam, c);
  const int wg = (tid >> 5) & 15, wc = (tid >> 3) & 3;
  const int waddr = hx_gran_off(wg, wc) + (tid & 7) * 2;  // my h[tid] slot

  // init h exchange buffer with h0
  *(u16*)(hxc + waddr) =
      __builtin_bit_cast(u16, (_Float16)h0[((isL0 ? 0 : 1) * NB + b) * NH + tid]);
  __syncthreads();

  const u16* pin = (isL0 ? pre0 : pre1) + (size_t)b * TSEQ * NH;
  u32* o0p = out0 + (size_t)b * TSEQ * 256;
  int* flagOut0 = flags + (40 + b) * 32;
  const int* f0 = flags + (b * 2 + 0) * 32;       // pre0 halves (L0)
  const int* f1 = flags + (b * 2 + 1) * 32;
  const int* fpA = flags + (60 + b * 4 + 0) * 32; // pre1 subs (L1)
  const int* fpB = flags + (60 + b * 4 + 1) * 32;
  const int* fpC = flags + (60 + b * 4 + 2) * 32;
  const int* fpD = flags + (60 + b * 4 + 3) * 32;
  int s0 = 0, s1 = 0, sA = 0, sB = 0, sC = 0, sD = 0;

  if (isL0) { while (s0 < 1) s0 = acq(f0); }
  else      { while (sA < 1) sA = acq(fpA); }
  u16 pcur = pin[tid];

  float hlast = 0.f;
#pragma unroll 1
  for (int t = 0; t < TSEQ; t++) {
    // prefetch next pre-activation (issued early; hides under compute)
    u16 pnxt = 0;
    if (t + 1 < TSEQ) {
      if (isL0) {
        const int hf = (t + 1) >> 10, lc = (t + 1) & 1023;
        if (hf == 0) { while (s0 < lc + 1) s0 = acq(f0); }
        else         { while (s1 < lc + 1) s1 = acq(f1); }
      } else {
        const int tn = t + 1;
        const int cm = (tn >> 3) & 3;
        if (cm == 0)      { while (sA < tn + 1) sA = acq(fpA); }
        else if (cm == 1) { while (sB < tn + 1) sB = acq(fpB); }
        else if (cm == 2) { while (sC < tn + 1) sC = acq(fpC); }
        else              { while (sD < tn + 1) sD = acq(fpD); }
      }
      pnxt = pin[(size_t)(t + 1) * NH + tid];
    }

    float p[16];
#pragma unroll
    for (int i = 0; i < 16; i++) p[i] = 0.f;
#pragma unroll
    for (int c = 0; c < 4; c++) {
      const uint4 hv = *(const uint4*)(hxc + hadr[c]);
#pragma unroll
      for (int j = 0; j < 12; j++) {
        p[j] = dot2(wj[j][4*c+0], hv.x, p[j]);
        p[j] = dot2(wj[j][4*c+1], hv.y, p[j]);
        p[j] = dot2(wj[j][4*c+2], hv.z, p[j]);
        p[j] = dot2(wj[j][4*c+3], hv.w, p[j]);
      }
#pragma unroll
      for (int jj = 0; jj < 4; jj++) {
        const uint4 wv = WLw4[(jj * 4 + c) * 512 + tid];
        p[12+jj] = dot2(wv.x, hv.x, p[12+jj]);
        p[12+jj] = dot2(wv.y, hv.y, p[12+jj]);
        p[12+jj] = dot2(wv.z, hv.z, p[12+jj]);
        p[12+jj] = dot2(wv.w, hv.w, p[12+jj]);
      }
    }

    // butterfly reduce over the 16-lane row; lane lam ends with sum for n = tid
#pragma unroll
    for (int i = 0; i < 16; i++) p[i] = dpp_add<0x140>(p[i]);   // xor15
    const bool k3 = (tid & 8);
#pragma unroll
    for (int i = 0; i < 8; i++) p[i] = k3 ? p[i + 8] : p[i];
#pragma unroll
    for (int i = 0; i < 8; i++) p[i] = dpp_add<0x141>(p[i]);    // xor7
    const bool k2 = (tid & 4);
#pragma unroll
    for (int i = 0; i < 4; i++) p[i] = k2 ? p[i + 4] : p[i];
#pragma unroll
    for (int i = 0; i < 4; i++) p[i] = dpp_add<0x4E>(p[i]);     // xor2
    const bool k1 = (tid & 2);
    p[0] = k1 ? p[2] : p[0]; p[1] = k1 ? p[3] : p[1];
    p[0] = dpp_add<0xB1>(p[0]); p[1] = dpp_add<0xB1>(p[1]);     // xor1
    const float red = (tid & 1) ? p[1] : p[0];

    const float h = fast_tanh(red + bias + (float)__builtin_bit_cast(_Float16, pcur));
    hlast = h;
    const u16 h16 = __builtin_bit_cast(u16, (_Float16)h);

    __syncthreads();   // A: all hx reads done; prev-iter out0 stores drained (vmcnt0)
    if (isL0 && (t & 7) == 0 && t && tid == 0) rel(flagOut0, t);
    *(u16*)(hxc + waddr) = h16;
    __syncthreads();   // B: hx stable for next step

    if (isL0) {
      // pack (h[2k], h[2k+1]) via DPP xor1 and store from even lanes
      u32 v = (u32)h16;
      u32 nb = dpp_mov_u32<0xB1>(v);
      if (!(tid & 1)) o0p[(size_t)t * 256 + (tid >> 1)] = v | (nb << 16);
    }
    pcur = pnxt;
  }
  if (isL0) {
    __syncthreads();   // drain final out0 stores
    if (tid == 0) rel(flagOut0, TSEQ);
  } else {
    h1f[(size_t)b * NH + tid] = hlast;
  }
}

__global__ void fc_kernel(const float* __restrict__ h1f, const float* __restrict__ Wfc,
                          const float* __restrict__ bfc, float* __restrict__ out) {
  const int b = blockIdx.x, o = threadIdx.x;  // 20 blocks x 128 threads
  __shared__ float hs[NH];
  for (int i = o; i < NH; i += NOUT) hs[i] = h1f[(size_t)b * NH + i];
  __syncthreads();
  const float4* w4 = (const float4*)(Wfc + (size_t)o * NH);
  const float4* h4 = (const float4*)hs;
  float acc = bfc[o];
#pragma unroll 8
  for (int j = 0; j < NH / 4; j++) {
    float4 w = w4[j], h = h4[j];
    acc += w.x * h.x + w.y * h.y + w.z * h.z + w.w * h.w;
  }
  out[(size_t)b * NOUT + o] = acc;
}

extern "C" void kernel_launch(void* const* d_in, const int* in_sizes, int n_in,
                              void* d_out, int out_size, void* d_ws, size_t ws_size,
                              hipStream_t stream) {
  const float* x    = (const float*)d_in[0];
  const float* h0   = (const float*)d_in[1];
  const float* Wih0 = (const float*)d_in[2];
  const float* Whh0 = (const float*)d_in[3];
  const float* bih0 = (const float*)d_in[4];
  const float* bhh0 = (const float*)d_in[5];
  const float* Wih1 = (const float*)d_in[6];
  const float* Whh1 = (const float*)d_in[7];
  const float* bih1 = (const float*)d_in[8];
  const float* bhh1 = (const float*)d_in[9];
  const float* Wfc  = (const float*)d_in[10];
  const float* bfc  = (const float*)d_in[11];
  float* out = (float*)d_out;

  char* ws = (char*)d_ws;
  size_t off = 0;
  u16* pre0 = (u16*)(ws + off); off += (size_t)NB * TSEQ * NH * 2;
  u32* out0 = (u32*)(ws + off); off += (size_t)NB * TSEQ * (NH / 2) * 4;
  u16* pre1 = (u16*)(ws + off); off += (size_t)NB * TSEQ * NH * 2;
  float* h1f = (float*)(ws + off); off += (size_t)NB * NH * 4;
  int* flags = (int*)(ws + off);
  const size_t flagbytes = 160 * 32 * sizeof(int);

  hipMemsetAsync(flags, 0, flagbytes, stream);
  hipFuncSetAttribute((const void*)rnn_persist,
                      hipFuncAttributeMaxDynamicSharedMemorySize, SMEM_BYTES);
  rnn_persist<<<160, 512, SMEM_BYTES, stream>>>(
      x, h0, Wih0, Whh0, bih0, bhh0, Wih1, Whh1, bih1, bhh1,
      pre0, out0, pre1, h1f, flags);
  fc_kernel<<<NB, NOUT, 0, stream>>>(h1f, Wfc, bfc, out);
}

// Round 5
// 5066.227 us; speedup vs baseline: 1.8196x; 1.8196x over previous
//
#include <hip/hip_runtime.h>

#define TSEQ 2048
#define NB   20
#define NIN  256
#define NH   512
#define NOUT 128

typedef unsigned int   u32;
typedef unsigned short u16;
typedef _Float16 f16x2 __attribute__((ext_vector_type(2)));

// dynamic LDS layout
#define SM_W     0                 // 131072 B: WLw uint4[16][512] (recurrence) / WL uint2[32][512] (pre1)
#define SM_HX    131072            // 1024 B: h exchange, sigma-swizzled f16[512]
#define SM_INP   (131072 + 1024)   // 2048 B: u32 [2][256] input staging (pre roles)
#define SMEM_BYTES (131072 + 1024 + 2048)

__device__ __forceinline__ u32 packh2(float a, float b) {
  f16x2 p; p.x = (_Float16)a; p.y = (_Float16)b;
  return __builtin_bit_cast(u32, p);
}

__device__ __forceinline__ float dot2(u32 w, u32 h, float acc) {
  return __builtin_amdgcn_fdot2(__builtin_bit_cast(f16x2, w),
                                __builtin_bit_cast(f16x2, h), acc, false);
}

__device__ __forceinline__ int acq(const int* p) {
  return __hip_atomic_load(p, __ATOMIC_ACQUIRE, __HIP_MEMORY_SCOPE_AGENT);
}
__device__ __forceinline__ void rel(int* p, int v) {
  __hip_atomic_store(p, v, __ATOMIC_RELEASE, __HIP_MEMORY_SCOPE_AGENT);
}

// cross-lane add via DPP (VALU pipe, no LDS).
// 0xB1 quad_perm[1,0,3,2]=xor1, 0x4E quad_perm[2,3,0,1]=xor2,
// 0x124 row_ror:4, 0x128 row_ror:8 (rows are 16 lanes on gfx9+)
template<int CTRL>
__device__ __forceinline__ float dpp_add(float x) {
  int v = __builtin_amdgcn_update_dpp(0, __builtin_bit_cast(int, x), CTRL, 0xF, 0xF, true);
  return x + __builtin_bit_cast(float, v);
}

template<int CTRL>
__device__ __forceinline__ u32 dpp_mov_u32(u32 x) {
  return (u32)__builtin_amdgcn_update_dpp(0, (int)x, CTRL, 0xF, 0xF, true);
}

// all 16 lanes of each row-of-16 end with the sum over the 16-lane group
__device__ __forceinline__ float bfly_sum16(float a) {
  a = dpp_add<0xB1>(a);    // xor1
  a = dpp_add<0x4E>(a);    // xor2
  a = dpp_add<0x124>(a);   // +quad (l+4)
  a = dpp_add<0x128>(a);   // +half (l+8)
  return a;
}

__device__ __forceinline__ float fast_tanh(float x) {
  float xc = fminf(fmaxf(x, -15.f), 15.f);
  float e = __builtin_amdgcn_exp2f(xc * 2.8853900817779268f);  // exp(2x)
  return (e - 1.f) * __builtin_amdgcn_rcpf(e + 1.f);
}

// sigma-swizzle for hx: granule G (16B) -> physical byte offset.
// G = 4*g + c (g = h-index>>5 = lam, c = chunk). phys = 64*pi(g) + 16*(c ^ (g&3)),
// pi(g) = g ^ (g>>2). Verified round 4: SQ_LDS_BANK_CONFLICT -> 0.
__device__ __forceinline__ int hx_gran_off(int g, int c) {
  int pg = (g ^ (g >> 2)) & 15;
  return 64 * pg + 16 * (c ^ (g & 3));
}

// Persistent fused pipeline. grid = 160 blocks x 512 threads, 1 block/CU.
//  bid   0..39 : pre0 (b=bid>>1, half=bid&1)        pre0 = x@Wih0^T + bih0 (f16)
//  bid  40..59 : L0 recurrence (b=bid-40)           out0 = h packed f16 pairs
//  bid 60..139 : pre1 (b=(bid-60)>>2, sub=(bid-60)&3) 4-way t-chunked gather
//  bid140..159 : L1 recurrence (b=bid-140)          h1f = last h (f32)
__global__ __launch_bounds__(512, 2) void rnn_persist(
    const float* __restrict__ x,    const float* __restrict__ h0,
    const float* __restrict__ Wih0, const float* __restrict__ Whh0,
    const float* __restrict__ bih0, const float* __restrict__ bhh0,
    const float* __restrict__ Wih1, const float* __restrict__ Whh1,
    const float* __restrict__ bih1, const float* __restrict__ bhh1,
    u16* __restrict__ pre0, u32* __restrict__ out0,
    u16* __restrict__ pre1, float* __restrict__ h1f,
    int* __restrict__ flags)
{
  extern __shared__ char smem[];
  const int tid = threadIdx.x;
  const int bid = blockIdx.x;

  if (bid < 40) {
    // ---------------- pre0: x @ Wih0^T + bih0 (verified rounds 1-4) ----------------
    u32* inp = (u32*)(smem + SM_INP);
    const int b = bid >> 1, half = bid & 1, t0 = half * 1024;
    const int n = tid;
    u32 wr[128];
    const float4* W4 = (const float4*)(Wih0 + (size_t)n * NIN);
#pragma unroll
    for (int j = 0; j < 64; j++) {
      float4 w = W4[j];
      wr[2*j] = packh2(w.x, w.y); wr[2*j+1] = packh2(w.z, w.w);
    }
    const float bias = bih0[n];
    const float* xb = x + ((size_t)b * TSEQ + t0) * NIN;
    u16* op = pre0 + ((size_t)b * TSEQ + t0) * NH;

    float2 r = make_float2(0.f, 0.f);
    if (tid < 128) r = ((const float2*)xb)[tid];
    int cur = 0;
    for (int t = 0; t < 1024; t++) {
      if (tid < 128) inp[cur * 256 + tid] = packh2(r.x, r.y);
      __syncthreads();
      if (t + 1 < 1024 && tid < 128)
        r = ((const float2*)(xb + (size_t)(t + 1) * NIN))[tid];
      float a0 = bias, a1 = 0.f;
      const uint4* xp = (const uint4*)(inp + cur * 256);
#pragma unroll
      for (int j = 0; j < 32; j++) {
        uint4 hv = xp[j];
        a0 = dot2(wr[4*j+0], hv.x, a0); a1 = dot2(wr[4*j+1], hv.y, a1);
        a0 = dot2(wr[4*j+2], hv.z, a0); a1 = dot2(wr[4*j+3], hv.w, a1);
      }
      op[(size_t)t * NH + n] = __builtin_bit_cast(u16, (_Float16)(a0 + a1));
      cur ^= 1;
      if (((t + 1) & 7) == 0) {
        __syncthreads();
        if (tid == 0) rel(flags + bid * 32, t + 1);
      }
    }
    return;
  }

  if (bid >= 60 && bid < 140) {
    // ---------------- pre1: out0 @ Wih1^T + bih1, 4-way t-chunk split ----------------
    uint2* WL  = (uint2*)(smem + SM_W);
    u32*   inp = (u32*)(smem + SM_INP);
    const int b = (bid - 60) >> 2, sub = (bid - 60) & 3;
    const int n = tid;
    u32 wr[192];
    const float4* W4 = (const float4*)(Wih1 + (size_t)n * NH);
#pragma unroll
    for (int j = 0; j < 96; j++) {
      float4 w = W4[j];
      wr[2*j] = packh2(w.x, w.y); wr[2*j+1] = packh2(w.z, w.w);
    }
#pragma unroll
    for (int j2 = 0; j2 < 32; j2++) {
      float4 w = W4[96 + j2];
      WL[j2 * NH + n] = make_uint2(packh2(w.x, w.y), packh2(w.z, w.w));
    }
    const float bias = bih1[n];
    __syncthreads();

    const u32* ip = out0 + (size_t)b * TSEQ * 256;
    u16* op = pre1 + (size_t)b * TSEQ * NH;
    const int* flagOut0 = flags + (40 + b) * 32;
    int* flagMy = flags + (60 + b * 4 + sub) * 32;
    int seen = 0, cur = 0;
#pragma unroll 1
    for (int c = sub; c < TSEQ / 8; c += 4) {
      const int tbase = c * 8;
      while (seen < tbase + 8) seen = acq(flagOut0);
      u32 rin = (tid < 256) ? ip[(size_t)tbase * 256 + tid] : 0;
#pragma unroll 1
      for (int qq = 0; qq < 8; qq++) {
        const int t = tbase + qq;
        if (tid < 256) inp[cur * 256 + tid] = rin;
        __syncthreads();
        if (qq + 1 < 8 && tid < 256) rin = ip[(size_t)(t + 1) * 256 + tid];
        float a0 = bias, a1 = 0.f;
        const uint4* hp4 = (const uint4*)(inp + cur * 256);
#pragma unroll
        for (int j = 0; j < 48; j++) {
          uint4 hv = hp4[j];
          a0 = dot2(wr[4*j+0], hv.x, a0); a1 = dot2(wr[4*j+1], hv.y, a1);
          a0 = dot2(wr[4*j+2], hv.z, a0); a1 = dot2(wr[4*j+3], hv.w, a1);
        }
#pragma unroll
        for (int jj = 0; jj < 16; jj++) {
          uint4 hv = hp4[48 + jj];
          uint2 w0 = WL[(2*jj)   * NH + n];
          uint2 w1 = WL[(2*jj+1) * NH + n];
          a0 = dot2(w0.x, hv.x, a0); a1 = dot2(w0.y, hv.y, a1);
          a0 = dot2(w1.x, hv.z, a0); a1 = dot2(w1.y, hv.w, a1);
        }
        op[(size_t)t * NH + n] = __builtin_bit_cast(u16, (_Float16)(a0 + a1));
        cur ^= 1;
      }
      __syncthreads();
      if (tid == 0) rel(flagMy, tbase + 8);
    }
    return;
  }

  // ---------------- L0 / L1 recurrence: scatter + per-row DPP reduce ----------------
  const bool isL0 = (bid < 60);
  const int b = isL0 ? (bid - 40) : (bid - 140);
  const float* Wg = isL0 ? Whh0 : Whh1;
  const float* bp = isL0 ? bhh0 : bhh1;

  uint4* WLw4 = (uint4*)(smem + SM_W);  // slot s at (s*512 + tid), s = 0..15
  char*  hxc  = smem + SM_HX;           // sigma-swizzled f16[512]

  const int lam = tid & 15;             // k-group: k in [32*lam, 32*lam+32)
  const int ns  = tid >> 4;             // n-slice: rows 16*ns .. 16*ns+15

  // Weights rows 0..11 -> registers (static indices only)
  u32 wj[12][16];
#pragma unroll
  for (int j = 0; j < 12; j++) {
    const float4* Wr = (const float4*)(Wg + (size_t)(16 * ns + j) * NH + 32 * lam);
#pragma unroll
    for (int k4 = 0; k4 < 8; k4++) {
      float4 w = Wr[k4];
      wj[j][2*k4] = packh2(w.x, w.y); wj[j][2*k4+1] = packh2(w.z, w.w);
    }
  }
  // Weights rows 12..15 -> LDS. Slot s = (j-12)*4 + q holds chunk-q u32s.
#pragma unroll
  for (int j = 12; j < 16; j++) {
    const float4* Wr = (const float4*)(Wg + (size_t)(16 * ns + j) * NH + 32 * lam);
#pragma unroll
    for (int q = 0; q < 4; q++) {
      float4 wA = Wr[2*q], wB = Wr[2*q+1];
      WLw4[((j - 12) * 4 + q) * 512 + tid] =
          make_uint4(packh2(wA.x, wA.y), packh2(wA.z, wA.w),
                     packh2(wB.x, wB.y), packh2(wB.z, wB.w));
    }
  }
  const float bias = bp[tid];           // final owner n == tid

  // precomputed hx addresses (loop-invariant)
  int hadr[4];
#pragma unroll
  for (int c = 0; c < 4; c++) hadr[c] = hx_gran_off(lam, c);
  const int wg = (tid >> 5) & 15, wc = (tid >> 3) & 3;
  const int waddr = hx_gran_off(wg, wc) + (tid & 7) * 2;  // my h[tid] slot

  // init h exchange buffer with h0
  *(u16*)(hxc + waddr) =
      __builtin_bit_cast(u16, (_Float16)h0[((isL0 ? 0 : 1) * NB + b) * NH + tid]);
  __syncthreads();

  const u16* pin = (isL0 ? pre0 : pre1) + (size_t)b * TSEQ * NH;
  u32* o0p = out0 + (size_t)b * TSEQ * 256;
  int* flagOut0 = flags + (40 + b) * 32;
  const int* f0 = flags + (b * 2 + 0) * 32;       // pre0 halves (L0)
  const int* f1 = flags + (b * 2 + 1) * 32;
  const int* fpA = flags + (60 + b * 4 + 0) * 32; // pre1 subs (L1)
  const int* fpB = flags + (60 + b * 4 + 1) * 32;
  const int* fpC = flags + (60 + b * 4 + 2) * 32;
  const int* fpD = flags + (60 + b * 4 + 3) * 32;
  int s0 = 0, s1 = 0, sA = 0, sB = 0, sC = 0, sD = 0;

  if (isL0) { while (s0 < 1) s0 = acq(f0); }
  else      { while (sA < 1) sA = acq(fpA); }
  u16 pcur = pin[tid];

  float hlast = 0.f;
#pragma unroll 1
  for (int t = 0; t < TSEQ; t++) {
    // prefetch next pre-activation (issued early; hides under compute)
    u16 pnxt = 0;
    if (t + 1 < TSEQ) {
      if (isL0) {
        const int hf = (t + 1) >> 10, lc = (t + 1) & 1023;
        if (hf == 0) { while (s0 < lc + 1) s0 = acq(f0); }
        else         { while (s1 < lc + 1) s1 = acq(f1); }
      } else {
        const int tn = t + 1;
        const int cm = (tn >> 3) & 3;
        if (cm == 0)      { while (sA < tn + 1) sA = acq(fpA); }
        else if (cm == 1) { while (sB < tn + 1) sB = acq(fpB); }
        else if (cm == 2) { while (sC < tn + 1) sC = acq(fpC); }
        else              { while (sD < tn + 1) sD = acq(fpD); }
      }
      pnxt = pin[(size_t)(t + 1) * NH + tid];
    }

    // hoist the 4 h-granules once per step (16 u32 live)
    const uint4 hv0 = *(const uint4*)(hxc + hadr[0]);
    const uint4 hv1 = *(const uint4*)(hxc + hadr[1]);
    const uint4 hv2 = *(const uint4*)(hxc + hadr[2]);
    const uint4 hv3 = *(const uint4*)(hxc + hadr[3]);

    float red = 0.f;
    // register rows: one scalar acc per row, reduce immediately (no p[] array)
#pragma unroll
    for (int j = 0; j < 12; j++) {
      float a = 0.f;
      a = dot2(wj[j][0],  hv0.x, a); a = dot2(wj[j][1],  hv0.y, a);
      a = dot2(wj[j][2],  hv0.z, a); a = dot2(wj[j][3],  hv0.w, a);
      a = dot2(wj[j][4],  hv1.x, a); a = dot2(wj[j][5],  hv1.y, a);
      a = dot2(wj[j][6],  hv1.z, a); a = dot2(wj[j][7],  hv1.w, a);
      a = dot2(wj[j][8],  hv2.x, a); a = dot2(wj[j][9],  hv2.y, a);
      a = dot2(wj[j][10], hv2.z, a); a = dot2(wj[j][11], hv2.w, a);
      a = dot2(wj[j][12], hv3.x, a); a = dot2(wj[j][13], hv3.y, a);
      a = dot2(wj[j][14], hv3.z, a); a = dot2(wj[j][15], hv3.w, a);
      a = bfly_sum16(a);
      red = (lam == j) ? a : red;
    }
    // LDS rows 12..15
#pragma unroll
    for (int j = 0; j < 4; j++) {
      const uint4 wv0 = WLw4[(j * 4 + 0) * 512 + tid];
      const uint4 wv1 = WLw4[(j * 4 + 1) * 512 + tid];
      const uint4 wv2 = WLw4[(j * 4 + 2) * 512 + tid];
      const uint4 wv3 = WLw4[(j * 4 + 3) * 512 + tid];
      float a = 0.f;
      a = dot2(wv0.x, hv0.x, a); a = dot2(wv0.y, hv0.y, a);
      a = dot2(wv0.z, hv0.z, a); a = dot2(wv0.w, hv0.w, a);
      a = dot2(wv1.x, hv1.x, a); a = dot2(wv1.y, hv1.y, a);
      a = dot2(wv1.z, hv1.z, a); a = dot2(wv1.w, hv1.w, a);
      a = dot2(wv2.x, hv2.x, a); a = dot2(wv2.y, hv2.y, a);
      a = dot2(wv2.z, hv2.z, a); a = dot2(wv2.w, hv2.w, a);
      a = dot2(wv3.x, hv3.x, a); a = dot2(wv3.y, hv3.y, a);
      a = dot2(wv3.z, hv3.z, a); a = dot2(wv3.w, hv3.w, a);
      a = bfly_sum16(a);
      red = (lam == 12 + j) ? a : red;
    }

    const float h = fast_tanh(red + bias + (float)__builtin_bit_cast(_Float16, pcur));
    hlast = h;
    const u16 h16 = __builtin_bit_cast(u16, (_Float16)h);

    __syncthreads();   // A: all hx reads done; prev-iter out0 stores drained
    if (isL0 && (t & 7) == 0 && t && tid == 0) rel(flagOut0, t);
    *(u16*)(hxc + waddr) = h16;
    __syncthreads();   // B: hx stable for next step

    if (isL0) {
      // pack (h[2k], h[2k+1]) via DPP xor1 and store from even lanes
      u32 v = (u32)h16;
      u32 nb = dpp_mov_u32<0xB1>(v);
      if (!(tid & 1)) o0p[(size_t)t * 256 + (tid >> 1)] = v | (nb << 16);
    }
    pcur = pnxt;
  }
  if (isL0) {
    __syncthreads();   // drain final out0 stores
    if (tid == 0) rel(flagOut0, TSEQ);
  } else {
    h1f[(size_t)b * NH + tid] = hlast;
  }
}

__global__ void fc_kernel(const float* __restrict__ h1f, const float* __restrict__ Wfc,
                          const float* __restrict__ bfc, float* __restrict__ out) {
  const int b = blockIdx.x, o = threadIdx.x;  // 20 blocks x 128 threads
  __shared__ float hs[NH];
  for (int i = o; i < NH; i += NOUT) hs[i] = h1f[(size_t)b * NH + i];
  __syncthreads();
  const float4* w4 = (const float4*)(Wfc + (size_t)o * NH);
  const float4* h4 = (const float4*)hs;
  float acc = bfc[o];
#pragma unroll 8
  for (int j = 0; j < NH / 4; j++) {
    float4 w = w4[j], h = h4[j];
    acc += w.x * h.x + w.y * h.y + w.z * h.z + w.w * h.w;
  }
  out[(size_t)b * NOUT + o] = acc;
}

extern "C" void kernel_launch(void* const* d_in, const int* in_sizes, int n_in,
                              void* d_out, int out_size, void* d_ws, size_t ws_size,
                              hipStream_t stream) {
  const float* x    = (const float*)d_in[0];
  const float* h0   = (const float*)d_in[1];
  const float* Wih0 = (const float*)d_in[2];
  const float* Whh0 = (const float*)d_in[3];
  const float* bih0 = (const float*)d_in[4];
  const float* bhh0 = (const float*)d_in[5];
  const float* Wih1 = (const float*)d_in[6];
  const float* Whh1 = (const float*)d_in[7];
  const float* bih1 = (const float*)d_in[8];
  const float* bhh1 = (const float*)d_in[9];
  const float* Wfc  = (const float*)d_in[10];
  const float* bfc  = (const float*)d_in[11];
  float* out = (float*)d_out;

  char* ws = (char*)d_ws;
  size_t off = 0;
  u16* pre0 = (u16*)(ws + off); off += (size_t)NB * TSEQ * NH * 2;
  u32* out0 = (u32*)(ws + off); off += (size_t)NB * TSEQ * (NH / 2) * 4;
  u16* pre1 = (u16*)(ws + off); off += (size_t)NB * TSEQ * NH * 2;
  float* h1f = (float*)(ws + off); off += (size_t)NB * NH * 4;
  int* flags = (int*)(ws + off);
  const size_t flagbytes = 160 * 32 * sizeof(int);

  hipMemsetAsync(flags, 0, flagbytes, stream);
  hipFuncSetAttribute((const void*)rnn_persist,
                      hipFuncAttributeMaxDynamicSharedMemorySize, SMEM_BYTES);
  rnn_persist<<<160, 512, SMEM_BYTES, stream>>>(
      x, h0, Wih0, Whh0, bih0, bhh0, Wih1, Whh1, bih1, bhh1,
      pre0, out0, pre1, h1f, flags);
  fc_kernel<<<NB, NOUT, 0, stream>>>(h1f, Wfc, bfc, out);
}

// Round 6
// 4235.806 us; speedup vs baseline: 2.1764x; 1.1960x over previous
//
#include <hip/hip_runtime.h>

#define TSEQ 2048
#define NB   20
#define NIN  256
#define NH   512
#define NOUT 128

typedef unsigned int   u32;
typedef unsigned short u16;
typedef _Float16 f16x2 __attribute__((ext_vector_type(2)));

// dynamic LDS layout
#define SM_W     0                 // 131072 B: WLw uint4[16][512] (recurrence) / WL uint2[32][512] (pre1)
#define SM_HX    131072            // 2048 B: h exchange, TWO sigma-swizzled f16[512] buffers
#define SM_INP   (131072 + 2048)   // 2048 B: u32 [2][256] input staging (pre roles)
#define SMEM_BYTES (131072 + 2048 + 2048)

__device__ __forceinline__ u32 packh2(float a, float b) {
  f16x2 p; p.x = (_Float16)a; p.y = (_Float16)b;
  return __builtin_bit_cast(u32, p);
}

__device__ __forceinline__ float dot2(u32 w, u32 h, float acc) {
  return __builtin_amdgcn_fdot2(__builtin_bit_cast(f16x2, w),
                                __builtin_bit_cast(f16x2, h), acc, false);
}

__device__ __forceinline__ int acq(const int* p) {
  return __hip_atomic_load(p, __ATOMIC_ACQUIRE, __HIP_MEMORY_SCOPE_AGENT);
}
__device__ __forceinline__ void rel(int* p, int v) {
  __hip_atomic_store(p, v, __ATOMIC_RELEASE, __HIP_MEMORY_SCOPE_AGENT);
}

// LDS-only barrier: orders LDS ops across the workgroup WITHOUT draining vmcnt
// (so in-flight global stores / prefetch loads stay in flight across steps).
__device__ __forceinline__ void lds_barrier() {
  asm volatile("s_waitcnt lgkmcnt(0)\n\ts_barrier" ::: "memory");
}

// cross-lane add via DPP (VALU pipe, no LDS).
// 0xB1 quad_perm[1,0,3,2]=xor1, 0x4E quad_perm[2,3,0,1]=xor2,
// 0x124 row_ror:4, 0x128 row_ror:8 (rows are 16 lanes on gfx9+)
template<int CTRL>
__device__ __forceinline__ float dpp_add(float x) {
  int v = __builtin_amdgcn_update_dpp(0, __builtin_bit_cast(int, x), CTRL, 0xF, 0xF, true);
  return x + __builtin_bit_cast(float, v);
}

template<int CTRL>
__device__ __forceinline__ u32 dpp_mov_u32(u32 x) {
  return (u32)__builtin_amdgcn_update_dpp(0, (int)x, CTRL, 0xF, 0xF, true);
}

// all 16 lanes of each row-of-16 end with the sum over the 16-lane group
__device__ __forceinline__ float bfly_sum16(float a) {
  a = dpp_add<0xB1>(a);    // xor1
  a = dpp_add<0x4E>(a);    // xor2
  a = dpp_add<0x124>(a);   // +quad (l+4)
  a = dpp_add<0x128>(a);   // +half (l+8)
  return a;
}

__device__ __forceinline__ float fast_tanh(float x) {
  float xc = fminf(fmaxf(x, -15.f), 15.f);
  float e = __builtin_amdgcn_exp2f(xc * 2.8853900817779268f);  // exp(2x)
  return (e - 1.f) * __builtin_amdgcn_rcpf(e + 1.f);
}

// sigma-swizzle for hx: granule G (16B) -> physical byte offset.
// G = 4*g + c (g = h-index>>5 = lam, c = chunk). phys = 64*pi(g) + 16*(c ^ (g&3)),
// pi(g) = g ^ (g>>2). Verified round 4/5: SQ_LDS_BANK_CONFLICT = 0.
__device__ __forceinline__ int hx_gran_off(int g, int c) {
  int pg = (g ^ (g >> 2)) & 15;
  return 64 * pg + 16 * (c ^ (g & 3));
}

// Persistent fused pipeline. grid = 160 blocks x 512 threads, 1 block/CU.
//  bid   0..39 : pre0 (b=bid>>1, half=bid&1)        pre0 = x@Wih0^T + bih0 (f16, 8-t tiles)
//  bid  40..59 : L0 recurrence (b=bid-40)           out0 = h packed f16 pairs
//  bid 60..139 : pre1 (b=(bid-60)>>2, sub=(bid-60)&3) 4-way t-chunked gather (8-t tiles)
//  bid140..159 : L1 recurrence (b=bid-140)          h1f = last h (f32)
//
// pre0/pre1 buffers are tiled [chunk][n][8] f16 so the recurrence loads ONE
// coalesced uint4 per thread per 8 steps (no per-step global load).
__global__ __launch_bounds__(512, 2) void rnn_persist(
    const float* __restrict__ x,    const float* __restrict__ h0,
    const float* __restrict__ Wih0, const float* __restrict__ Whh0,
    const float* __restrict__ bih0, const float* __restrict__ bhh0,
    const float* __restrict__ Wih1, const float* __restrict__ Whh1,
    const float* __restrict__ bih1, const float* __restrict__ bhh1,
    u16* __restrict__ pre0, u32* __restrict__ out0,
    u16* __restrict__ pre1, float* __restrict__ h1f,
    int* __restrict__ flags)
{
  extern __shared__ char smem[];
  const int tid = threadIdx.x;
  const int bid = blockIdx.x;

  if (bid < 40) {
    // ---------------- pre0: x @ Wih0^T + bih0 (tiled store) ----------------
    u32* inp = (u32*)(smem + SM_INP);
    const int b = bid >> 1, half = bid & 1, t0 = half * 1024;
    const int n = tid;
    u32 wr[128];
    const float4* W4 = (const float4*)(Wih0 + (size_t)n * NIN);
#pragma unroll
    for (int j = 0; j < 64; j++) {
      float4 w = W4[j];
      wr[2*j] = packh2(w.x, w.y); wr[2*j+1] = packh2(w.z, w.w);
    }
    const float bias = bih0[n];
    const float* xb = x + ((size_t)b * TSEQ + t0) * NIN;
    u16* op = pre0 + ((size_t)b * TSEQ + t0) * NH;

    float2 r = make_float2(0.f, 0.f);
    if (tid < 128) r = ((const float2*)xb)[tid];
    int cur = 0;
    for (int t = 0; t < 1024; t++) {
      if (tid < 128) inp[cur * 256 + tid] = packh2(r.x, r.y);
      __syncthreads();
      if (t + 1 < 1024 && tid < 128)
        r = ((const float2*)(xb + (size_t)(t + 1) * NIN))[tid];
      float a0 = bias, a1 = 0.f;
      const uint4* xp = (const uint4*)(inp + cur * 256);
#pragma unroll
      for (int j = 0; j < 32; j++) {
        uint4 hv = xp[j];
        a0 = dot2(wr[4*j+0], hv.x, a0); a1 = dot2(wr[4*j+1], hv.y, a1);
        a0 = dot2(wr[4*j+2], hv.z, a0); a1 = dot2(wr[4*j+3], hv.w, a1);
      }
      op[((size_t)(t >> 3) * NH + n) * 8 + (t & 7)] =
          __builtin_bit_cast(u16, (_Float16)(a0 + a1));
      cur ^= 1;
      if (((t + 1) & 7) == 0) {
        __syncthreads();
        if (tid == 0) rel(flags + bid * 32, t + 1);
      }
    }
    return;
  }

  if (bid >= 60 && bid < 140) {
    // ---------------- pre1: out0 @ Wih1^T + bih1, 4-way t-chunk split ----------------
    uint2* WL  = (uint2*)(smem + SM_W);
    u32*   inp = (u32*)(smem + SM_INP);
    const int b = (bid - 60) >> 2, sub = (bid - 60) & 3;
    const int n = tid;
    u32 wr[192];
    const float4* W4 = (const float4*)(Wih1 + (size_t)n * NH);
#pragma unroll
    for (int j = 0; j < 96; j++) {
      float4 w = W4[j];
      wr[2*j] = packh2(w.x, w.y); wr[2*j+1] = packh2(w.z, w.w);
    }
#pragma unroll
    for (int j2 = 0; j2 < 32; j2++) {
      float4 w = W4[96 + j2];
      WL[j2 * NH + n] = make_uint2(packh2(w.x, w.y), packh2(w.z, w.w));
    }
    const float bias = bih1[n];
    __syncthreads();

    const u32* ip = out0 + (size_t)b * TSEQ * 256;
    u16* op = pre1 + (size_t)b * TSEQ * NH;
    const int* flagOut0 = flags + (40 + b) * 32;
    int* flagMy = flags + (60 + b * 4 + sub) * 32;
    int seen = 0, cur = 0;
#pragma unroll 1
    for (int c = sub; c < TSEQ / 8; c += 4) {
      const int tbase = c * 8;
      while (seen < tbase + 8) seen = acq(flagOut0);
      u32 rin = (tid < 256) ? ip[(size_t)tbase * 256 + tid] : 0;
#pragma unroll 1
      for (int qq = 0; qq < 8; qq++) {
        const int t = tbase + qq;
        if (tid < 256) inp[cur * 256 + tid] = rin;
        __syncthreads();
        if (qq + 1 < 8 && tid < 256) rin = ip[(size_t)(t + 1) * 256 + tid];
        float a0 = bias, a1 = 0.f;
        const uint4* hp4 = (const uint4*)(inp + cur * 256);
#pragma unroll
        for (int j = 0; j < 48; j++) {
          uint4 hv = hp4[j];
          a0 = dot2(wr[4*j+0], hv.x, a0); a1 = dot2(wr[4*j+1], hv.y, a1);
          a0 = dot2(wr[4*j+2], hv.z, a0); a1 = dot2(wr[4*j+3], hv.w, a1);
        }
#pragma unroll
        for (int jj = 0; jj < 16; jj++) {
          uint4 hv = hp4[48 + jj];
          uint2 w0 = WL[(2*jj)   * NH + n];
          uint2 w1 = WL[(2*jj+1) * NH + n];
          a0 = dot2(w0.x, hv.x, a0); a1 = dot2(w0.y, hv.y, a1);
          a0 = dot2(w1.x, hv.z, a0); a1 = dot2(w1.y, hv.w, a1);
        }
        op[((size_t)(t >> 3) * NH + n) * 8 + (t & 7)] =
            __builtin_bit_cast(u16, (_Float16)(a0 + a1));
        cur ^= 1;
      }
      __syncthreads();
      if (tid == 0) rel(flagMy, tbase + 8);
    }
    return;
  }

  // ---------------- L0 / L1 recurrence: scatter + per-row DPP reduce ----------------
  const bool isL0 = (bid < 60);
  const int b = isL0 ? (bid - 40) : (bid - 140);
  const float* Wg = isL0 ? Whh0 : Whh1;
  const float* bp = isL0 ? bhh0 : bhh1;

  uint4* WLw4 = (uint4*)(smem + SM_W);  // slot s at (s*512 + tid), s = 0..15
  char*  hxc  = smem + SM_HX;           // 2x sigma-swizzled f16[512]

  const int lam = tid & 15;             // k-group: k in [32*lam, 32*lam+32)
  const int ns  = tid >> 4;             // n-slice: rows 16*ns .. 16*ns+15

  // Weights rows 0..11 -> registers (static indices only; verified round 5)
  u32 wj[12][16];
#pragma unroll
  for (int j = 0; j < 12; j++) {
    const float4* Wr = (const float4*)(Wg + (size_t)(16 * ns + j) * NH + 32 * lam);
#pragma unroll
    for (int k4 = 0; k4 < 8; k4++) {
      float4 w = Wr[k4];
      wj[j][2*k4] = packh2(w.x, w.y); wj[j][2*k4+1] = packh2(w.z, w.w);
    }
  }
  // Weights rows 12..15 -> LDS. Slot s = (j-12)*4 + q holds chunk-q u32s.
#pragma unroll
  for (int j = 12; j < 16; j++) {
    const float4* Wr = (const float4*)(Wg + (size_t)(16 * ns + j) * NH + 32 * lam);
#pragma unroll
    for (int q = 0; q < 4; q++) {
      float4 wA = Wr[2*q], wB = Wr[2*q+1];
      WLw4[((j - 12) * 4 + q) * 512 + tid] =
          make_uint4(packh2(wA.x, wA.y), packh2(wA.z, wA.w),
                     packh2(wB.x, wB.y), packh2(wB.z, wB.w));
    }
  }
  const float bias = bp[tid];           // final owner n == tid

  // precomputed hx addresses (loop-invariant, static-indexed)
  int hadr[4];
#pragma unroll
  for (int c = 0; c < 4; c++) hadr[c] = hx_gran_off(lam, c);
  const int wg = (tid >> 5) & 15, wc = (tid >> 3) & 3;
  const int waddr = hx_gran_off(wg, wc) + (tid & 7) * 2;  // my h[tid] slot

  // init h exchange buffer 0 with h0
  *(u16*)(hxc + waddr) =
      __builtin_bit_cast(u16, (_Float16)h0[((isL0 ? 0 : 1) * NB + b) * NH + tid]);
  __syncthreads();

  const uint4* pin4 =
      (const uint4*)((isL0 ? pre0 : pre1) + (size_t)b * TSEQ * NH);
  u32* o0p = out0 + (size_t)b * TSEQ * 256;
  int* flagOut0 = flags + (40 + b) * 32;
  const int* f0 = flags + (b * 2 + 0) * 32;       // pre0 halves (L0)
  const int* f1 = flags + (b * 2 + 1) * 32;
  const int* fpA = flags + (60 + b * 4 + 0) * 32; // pre1 subs (L1)
  const int* fpB = flags + (60 + b * 4 + 1) * 32;
  const int* fpC = flags + (60 + b * 4 + 2) * 32;
  const int* fpD = flags + (60 + b * 4 + 3) * 32;
  int s0 = 0, s1 = 0, sA = 0, sB = 0, sC = 0, sD = 0;

  // prologue: fetch chunk 0 into pcur4, chunk 1 into pnext4
  if (isL0) { while (s0 < 8)  s0 = acq(f0); }
  else      { while (sA < 8)  sA = acq(fpA); }
  uint4 pcur4 = pin4[tid];
  if (isL0) { while (s0 < 16) s0 = acq(f0); }
  else      { while (sB < 16) sB = acq(fpB); }
  uint4 pnext4 = pin4[512 + tid];

  float hlast = 0.f;
#pragma unroll 1
  for (int c = 0; c < TSEQ / 8; c++) {
#pragma unroll 1
    for (int q = 0; q < 8; q++) {
      const int t = c * 8 + q;
      const int rbase = (t & 1) << 10;   // read buffer
      const int wbase = rbase ^ 1024;    // write buffer

      const uint4 hv0 = *(const uint4*)(hxc + rbase + hadr[0]);
      const uint4 hv1 = *(const uint4*)(hxc + rbase + hadr[1]);
      const uint4 hv2 = *(const uint4*)(hxc + rbase + hadr[2]);
      const uint4 hv3 = *(const uint4*)(hxc + rbase + hadr[3]);

      float red = 0.f;
#pragma unroll
      for (int j = 0; j < 12; j++) {
        float a = 0.f;
        a = dot2(wj[j][0],  hv0.x, a); a = dot2(wj[j][1],  hv0.y, a);
        a = dot2(wj[j][2],  hv0.z, a); a = dot2(wj[j][3],  hv0.w, a);
        a = dot2(wj[j][4],  hv1.x, a); a = dot2(wj[j][5],  hv1.y, a);
        a = dot2(wj[j][6],  hv1.z, a); a = dot2(wj[j][7],  hv1.w, a);
        a = dot2(wj[j][8],  hv2.x, a); a = dot2(wj[j][9],  hv2.y, a);
        a = dot2(wj[j][10], hv2.z, a); a = dot2(wj[j][11], hv2.w, a);
        a = dot2(wj[j][12], hv3.x, a); a = dot2(wj[j][13], hv3.y, a);
        a = dot2(wj[j][14], hv3.z, a); a = dot2(wj[j][15], hv3.w, a);
        a = bfly_sum16(a);
        red = (lam == j) ? a : red;
      }
#pragma unroll
      for (int j = 0; j < 4; j++) {
        const uint4 wv0 = WLw4[(j * 4 + 0) * 512 + tid];
        const uint4 wv1 = WLw4[(j * 4 + 1) * 512 + tid];
        const uint4 wv2 = WLw4[(j * 4 + 2) * 512 + tid];
        const uint4 wv3 = WLw4[(j * 4 + 3) * 512 + tid];
        float a = 0.f;
        a = dot2(wv0.x, hv0.x, a); a = dot2(wv0.y, hv0.y, a);
        a = dot2(wv0.z, hv0.z, a); a = dot2(wv0.w, hv0.w, a);
        a = dot2(wv1.x, hv1.x, a); a = dot2(wv1.y, hv1.y, a);
        a = dot2(wv1.z, hv1.z, a); a = dot2(wv1.w, hv1.w, a);
        a = dot2(wv2.x, hv2.x, a); a = dot2(wv2.y, hv2.y, a);
        a = dot2(wv2.z, hv2.z, a); a = dot2(wv2.w, hv2.w, a);
        a = dot2(wv3.x, hv3.x, a); a = dot2(wv3.y, hv3.y, a);
        a = dot2(wv3.z, hv3.z, a); a = dot2(wv3.w, hv3.w, a);
        a = bfly_sum16(a);
        red = (lam == 12 + j) ? a : red;
      }

      // extract pre-activation q from pcur4 (selects only, no array indexing)
      const u32 wlo  = (q & 4) ? pcur4.z : pcur4.x;
      const u32 whi  = (q & 4) ? pcur4.w : pcur4.y;
      const u32 wsel = (q & 2) ? whi : wlo;
      const u16 pq   = (u16)((q & 1) ? (wsel >> 16) : (wsel & 0xffffu));

      const float h = fast_tanh(red + bias + (float)__builtin_bit_cast(_Float16, pq));
      hlast = h;
      const u16 h16 = __builtin_bit_cast(u16, (_Float16)h);
      *(u16*)(hxc + wbase + waddr) = h16;

      if (isL0) {
        // pack (h[2k], h[2k+1]) via DPP xor1 and store from even lanes
        u32 v = (u32)h16;
        u32 nb = dpp_mov_u32<0xB1>(v);
        if (!(tid & 1)) o0p[(size_t)t * 256 + (tid >> 1)] = v | (nb << 16);
      }

      if (q == 7) __syncthreads();  // full drain (vm for flag release, bounds stores)
      else        lds_barrier();    // LDS-only ordering; vm ops stay in flight
    }

    if (isL0 && tid == 0) rel(flagOut0, c * 8 + 8);

    // rotate chunk buffers, prefetch chunk c+2
    pcur4 = pnext4;
    if (c < TSEQ / 8 - 2) {
      const int c2 = c + 2;
      const int need = 8 * (c2 + 1);
      if (isL0) {
        if (c2 < 128) { while (s0 < need)        s0 = acq(f0); }
        else          { while (s1 < need - 1024) s1 = acq(f1); }
      } else {
        const int w = c2 & 3;
        if      (w == 0) { while (sA < need) sA = acq(fpA); }
        else if (w == 1) { while (sB < need) sB = acq(fpB); }
        else if (w == 2) { while (sC < need) sC = acq(fpC); }
        else             { while (sD < need) sD = acq(fpD); }
      }
      pnext4 = pin4[(size_t)c2 * 512 + tid];
    }
  }

  if (!isL0) h1f[(size_t)b * NH + tid] = hlast;
}

__global__ void fc_kernel(const float* __restrict__ h1f, const float* __restrict__ Wfc,
                          const float* __restrict__ bfc, float* __restrict__ out) {
  const int b = blockIdx.x, o = threadIdx.x;  // 20 blocks x 128 threads
  __shared__ float hs[NH];
  for (int i = o; i < NH; i += NOUT) hs[i] = h1f[(size_t)b * NH + i];
  __syncthreads();
  const float4* w4 = (const float4*)(Wfc + (size_t)o * NH);
  const float4* h4 = (const float4*)hs;
  float acc = bfc[o];
#pragma unroll 8
  for (int j = 0; j < NH / 4; j++) {
    float4 w = w4[j], h = h4[j];
    acc += w.x * h.x + w.y * h.y + w.z * h.z + w.w * h.w;
  }
  out[(size_t)b * NOUT + o] = acc;
}

extern "C" void kernel_launch(void* const* d_in, const int* in_sizes, int n_in,
                              void* d_out, int out_size, void* d_ws, size_t ws_size,
                              hipStream_t stream) {
  const float* x    = (const float*)d_in[0];
  const float* h0   = (const float*)d_in[1];
  const float* Wih0 = (const float*)d_in[2];
  const float* Whh0 = (const float*)d_in[3];
  const float* bih0 = (const float*)d_in[4];
  const float* bhh0 = (const float*)d_in[5];
  const float* Wih1 = (const float*)d_in[6];
  const float* Whh1 = (const float*)d_in[7];
  const float* bih1 = (const float*)d_in[8];
  const float* bhh1 = (const float*)d_in[9];
  const float* Wfc  = (const float*)d_in[10];
  const float* bfc  = (const float*)d_in[11];
  float* out = (float*)d_out;

  char* ws = (char*)d_ws;
  size_t off = 0;
  u16* pre0 = (u16*)(ws + off); off += (size_t)NB * TSEQ * NH * 2;
  u32* out0 = (u32*)(ws + off); off += (size_t)NB * TSEQ * (NH / 2) * 4;
  u16* pre1 = (u16*)(ws + off); off += (size_t)NB * TSEQ * NH * 2;
  float* h1f = (float*)(ws + off); off += (size_t)NB * NH * 4;
  int* flags = (int*)(ws + off);
  const size_t flagbytes = 160 * 32 * sizeof(int);

  hipMemsetAsync(flags, 0, flagbytes, stream);
  hipFuncSetAttribute((const void*)rnn_persist,
                      hipFuncAttributeMaxDynamicSharedMemorySize, SMEM_BYTES);
  rnn_persist<<<160, 512, SMEM_BYTES, stream>>>(
      x, h0, Wih0, Whh0, bih0, bhh0, Wih1, Whh1, bih1, bhh1,
      pre0, out0, pre1, h1f, flags);
  fc_kernel<<<NB, NOUT, 0, stream>>>(h1f, Wfc, bfc, out);
}

// Round 7
// 3636.057 us; speedup vs baseline: 2.5353x; 1.1649x over previous
//
#include <hip/hip_runtime.h>

#define TSEQ 2048
#define NB   20
#define NIN  256
#define NH   512
#define NOUT 128

typedef unsigned int   u32;
typedef unsigned short u16;
typedef _Float16 f16x2 __attribute__((ext_vector_type(2)));

// dynamic LDS layout
#define SM_W     0                 // 131072 B: WLw uint4[16][512] (recurrence) / WL uint2[32][512] (pre1)
#define SM_HX    131072            // 2048 B: h exchange, TWO sigma-swizzled f16[512] buffers
#define SM_INP   (131072 + 2048)   // 2048 B: u32 [2][256] input staging (pre roles)
#define SMEM_BYTES (131072 + 2048 + 2048)

__device__ __forceinline__ u32 packh2(float a, float b) {
  f16x2 p; p.x = (_Float16)a; p.y = (_Float16)b;
  return __builtin_bit_cast(u32, p);
}

__device__ __forceinline__ float dot2(u32 w, u32 h, float acc) {
  return __builtin_amdgcn_fdot2(__builtin_bit_cast(f16x2, w),
                                __builtin_bit_cast(f16x2, h), acc, false);
}

__device__ __forceinline__ int acq(const int* p) {
  return __hip_atomic_load(p, __ATOMIC_ACQUIRE, __HIP_MEMORY_SCOPE_AGENT);
}
__device__ __forceinline__ void rel(int* p, int v) {
  __hip_atomic_store(p, v, __ATOMIC_RELEASE, __HIP_MEMORY_SCOPE_AGENT);
}
// spin with s_sleep backoff (round-6 showed a 35ms outlier dispatch: spin storms)
__device__ __forceinline__ void spin_until(const int* p, int need, int& seen) {
  while (seen < need) {
    seen = acq(p);
    if (seen < need) __builtin_amdgcn_s_sleep(1);
  }
}

// LDS-only barrier: orders LDS ops across the workgroup WITHOUT draining vmcnt
// (so in-flight global stores / prefetch loads stay in flight across steps).
__device__ __forceinline__ void lds_barrier() {
  asm volatile("s_waitcnt lgkmcnt(0)\n\ts_barrier" ::: "memory");
}

// cross-lane add via DPP (VALU pipe, no LDS).
// 0xB1 quad_perm[1,0,3,2]=xor1, 0x4E quad_perm[2,3,0,1]=xor2,
// 0x124 row_ror:4, 0x128 row_ror:8 (rows are 16 lanes on gfx9+)
template<int CTRL>
__device__ __forceinline__ float dpp_add(float x) {
  int v = __builtin_amdgcn_update_dpp(0, __builtin_bit_cast(int, x), CTRL, 0xF, 0xF, true);
  return x + __builtin_bit_cast(float, v);
}

template<int CTRL>
__device__ __forceinline__ u32 dpp_mov_u32(u32 x) {
  return (u32)__builtin_amdgcn_update_dpp(0, (int)x, CTRL, 0xF, 0xF, true);
}

__device__ __forceinline__ float fast_tanh(float x) {
  float xc = fminf(fmaxf(x, -15.f), 15.f);
  float e = __builtin_amdgcn_exp2f(xc * 2.8853900817779268f);  // exp(2x)
  return (e - 1.f) * __builtin_amdgcn_rcpf(e + 1.f);
}

// sigma-swizzle for hx: granule G (16B) -> physical byte offset.
// G = 4*g + c (g = h-index>>5 = lam, c = chunk). phys = 64*pi(g) + 16*(c ^ (g&3)),
// pi(g) = g ^ (g>>2). Verified rounds 4-6: SQ_LDS_BANK_CONFLICT = 0.
__device__ __forceinline__ int hx_gran_off(int g, int c) {
  int pg = (g ^ (g >> 2)) & 15;
  return 64 * pg + 16 * (c ^ (g & 3));
}

// Persistent fused pipeline. grid = 160 blocks x 512 threads, 1 block/CU.
//  bid   0..39 : pre0 (b=bid>>1, half=bid&1)        pre0 = x@Wih0^T + bih0 (f16, 8-t tiles)
//  bid  40..59 : L0 recurrence (b=bid-40)           out0 = h packed f16 pairs
//  bid 60..139 : pre1 (b=(bid-60)>>2, sub=(bid-60)&3) 4-way t-chunked gather (8-t tiles)
//  bid140..159 : L1 recurrence (b=bid-140)          h1f = last h (f32)
__global__ __launch_bounds__(512, 2) void rnn_persist(
    const float* __restrict__ x,    const float* __restrict__ h0,
    const float* __restrict__ Wih0, const float* __restrict__ Whh0,
    const float* __restrict__ bih0, const float* __restrict__ bhh0,
    const float* __restrict__ Wih1, const float* __restrict__ Whh1,
    const float* __restrict__ bih1, const float* __restrict__ bhh1,
    u16* __restrict__ pre0, u32* __restrict__ out0,
    u16* __restrict__ pre1, float* __restrict__ h1f,
    int* __restrict__ flags)
{
  extern __shared__ char smem[];
  const int tid = threadIdx.x;
  const int bid = blockIdx.x;

  if (bid < 40) {
    // ---------------- pre0: x @ Wih0^T + bih0 (tiled store) ----------------
    u32* inp = (u32*)(smem + SM_INP);
    const int b = bid >> 1, half = bid & 1, t0 = half * 1024;
    const int n = tid;
    u32 wr[128];
    const float4* W4 = (const float4*)(Wih0 + (size_t)n * NIN);
#pragma unroll
    for (int j = 0; j < 64; j++) {
      float4 w = W4[j];
      wr[2*j] = packh2(w.x, w.y); wr[2*j+1] = packh2(w.z, w.w);
    }
    const float bias = bih0[n];
    const float* xb = x + ((size_t)b * TSEQ + t0) * NIN;
    u16* op = pre0 + ((size_t)b * TSEQ + t0) * NH;

    float2 r = make_float2(0.f, 0.f);
    if (tid < 128) r = ((const float2*)xb)[tid];
    int cur = 0;
    for (int t = 0; t < 1024; t++) {
      if (tid < 128) inp[cur * 256 + tid] = packh2(r.x, r.y);
      __syncthreads();
      if (t + 1 < 1024 && tid < 128)
        r = ((const float2*)(xb + (size_t)(t + 1) * NIN))[tid];
      float a0 = bias, a1 = 0.f;
      const uint4* xp = (const uint4*)(inp + cur * 256);
#pragma unroll
      for (int j = 0; j < 32; j++) {
        uint4 hv = xp[j];
        a0 = dot2(wr[4*j+0], hv.x, a0); a1 = dot2(wr[4*j+1], hv.y, a1);
        a0 = dot2(wr[4*j+2], hv.z, a0); a1 = dot2(wr[4*j+3], hv.w, a1);
      }
      op[((size_t)(t >> 3) * NH + n) * 8 + (t & 7)] =
          __builtin_bit_cast(u16, (_Float16)(a0 + a1));
      cur ^= 1;
      if (((t + 1) & 7) == 0) {
        __syncthreads();
        if (tid == 0) rel(flags + bid * 32, t + 1);
      }
    }
    return;
  }

  if (bid >= 60 && bid < 140) {
    // ---------------- pre1: out0 @ Wih1^T + bih1, 4-way t-chunk split ----------------
    uint2* WL  = (uint2*)(smem + SM_W);
    u32*   inp = (u32*)(smem + SM_INP);
    const int b = (bid - 60) >> 2, sub = (bid - 60) & 3;
    const int n = tid;
    u32 wr[192];
    const float4* W4 = (const float4*)(Wih1 + (size_t)n * NH);
#pragma unroll
    for (int j = 0; j < 96; j++) {
      float4 w = W4[j];
      wr[2*j] = packh2(w.x, w.y); wr[2*j+1] = packh2(w.z, w.w);
    }
#pragma unroll
    for (int j2 = 0; j2 < 32; j2++) {
      float4 w = W4[96 + j2];
      WL[j2 * NH + n] = make_uint2(packh2(w.x, w.y), packh2(w.z, w.w));
    }
    const float bias = bih1[n];
    __syncthreads();

    const u32* ip = out0 + (size_t)b * TSEQ * 256;
    u16* op = pre1 + (size_t)b * TSEQ * NH;
    const int* flagOut0 = flags + (40 + b) * 32;
    int* flagMy = flags + (60 + b * 4 + sub) * 32;
    int seen = 0, cur = 0;
#pragma unroll 1
    for (int c = sub; c < TSEQ / 8; c += 4) {
      const int tbase = c * 8;
      spin_until(flagOut0, tbase + 8, seen);
      u32 rin = (tid < 256) ? ip[(size_t)tbase * 256 + tid] : 0;
#pragma unroll 1
      for (int qq = 0; qq < 8; qq++) {
        const int t = tbase + qq;
        if (tid < 256) inp[cur * 256 + tid] = rin;
        __syncthreads();
        if (qq + 1 < 8 && tid < 256) rin = ip[(size_t)(t + 1) * 256 + tid];
        float a0 = bias, a1 = 0.f;
        const uint4* hp4 = (const uint4*)(inp + cur * 256);
#pragma unroll
        for (int j = 0; j < 48; j++) {
          uint4 hv = hp4[j];
          a0 = dot2(wr[4*j+0], hv.x, a0); a1 = dot2(wr[4*j+1], hv.y, a1);
          a0 = dot2(wr[4*j+2], hv.z, a0); a1 = dot2(wr[4*j+3], hv.w, a1);
        }
#pragma unroll
        for (int jj = 0; jj < 16; jj++) {
          uint4 hv = hp4[48 + jj];
          uint2 w0 = WL[(2*jj)   * NH + n];
          uint2 w1 = WL[(2*jj+1) * NH + n];
          a0 = dot2(w0.x, hv.x, a0); a1 = dot2(w0.y, hv.y, a1);
          a0 = dot2(w1.x, hv.z, a0); a1 = dot2(w1.y, hv.w, a1);
        }
        op[((size_t)(t >> 3) * NH + n) * 8 + (t & 7)] =
            __builtin_bit_cast(u16, (_Float16)(a0 + a1));
        cur ^= 1;
      }
      __syncthreads();
      if (tid == 0) rel(flagMy, tbase + 8);
    }
    return;
  }

  // ---------------- L0 / L1 recurrence: scatter + grouped DPP pairing tree ----------------
  const bool isL0 = (bid < 60);
  const int b = isL0 ? (bid - 40) : (bid - 140);
  const float* Wg = isL0 ? Whh0 : Whh1;
  const float* bp = isL0 ? bhh0 : bhh1;

  uint4* WLw4 = (uint4*)(smem + SM_W);  // slot s at (s*512 + tid), s = 0..15
  char*  hxc  = smem + SM_HX;           // 2x sigma-swizzled f16[512]

  const int lam = tid & 15;             // k-group: k in [32*lam, 32*lam+32)
  const int ns  = tid >> 4;             // n-slice: rows 16*ns .. 16*ns+15

  // Register rows: group g holds matrix rows 16*ns + {4g, 4g+1, 4g+2} in wj[3g+m].
  u32 wj[12][16];
#pragma unroll
  for (int g = 0; g < 4; g++) {
#pragma unroll
    for (int m = 0; m < 3; m++) {
      const float4* Wr = (const float4*)(Wg + (size_t)(16 * ns + 4 * g + m) * NH + 32 * lam);
#pragma unroll
      for (int k4 = 0; k4 < 8; k4++) {
        float4 w = Wr[k4];
        wj[3*g+m][2*k4] = packh2(w.x, w.y); wj[3*g+m][2*k4+1] = packh2(w.z, w.w);
      }
    }
  }
  // LDS rows: matrix row 16*ns + 4g+3 -> slots 4g + q (chunk q u32s).
#pragma unroll
  for (int g = 0; g < 4; g++) {
    const float4* Wr = (const float4*)(Wg + (size_t)(16 * ns + 4 * g + 3) * NH + 32 * lam);
#pragma unroll
    for (int q = 0; q < 4; q++) {
      float4 wA = Wr[2*q], wB = Wr[2*q+1];
      WLw4[(4 * g + q) * 512 + tid] =
          make_uint4(packh2(wA.x, wA.y), packh2(wA.z, wA.w),
                     packh2(wB.x, wB.y), packh2(wB.z, wB.w));
    }
  }
  const float bias = bp[tid];           // final owner n == tid

  // precomputed hx addresses (loop-invariant, static-indexed)
  int hadr[4];
#pragma unroll
  for (int c = 0; c < 4; c++) hadr[c] = hx_gran_off(lam, c);
  const int wg = (tid >> 5) & 15, wc = (tid >> 3) & 3;
  const int waddr = hx_gran_off(wg, wc) + (tid & 7) * 2;  // my h[tid] slot
  const bool b0 = (tid & 1), b1 = (tid & 2), b2 = (tid & 4), b3 = (tid & 8);

  // init h exchange buffer 0 with h0
  *(u16*)(hxc + waddr) =
      __builtin_bit_cast(u16, (_Float16)h0[((isL0 ? 0 : 1) * NB + b) * NH + tid]);
  __syncthreads();

  const uint4* pin4 =
      (const uint4*)((isL0 ? pre0 : pre1) + (size_t)b * TSEQ * NH);
  u32* o0p = out0 + (size_t)b * TSEQ * 256;
  int* flagOut0 = flags + (40 + b) * 32;
  const int* f0 = flags + (b * 2 + 0) * 32;       // pre0 halves (L0)
  const int* f1 = flags + (b * 2 + 1) * 32;
  const int* fpA = flags + (60 + b * 4 + 0) * 32; // pre1 subs (L1)
  const int* fpB = flags + (60 + b * 4 + 1) * 32;
  const int* fpC = flags + (60 + b * 4 + 2) * 32;
  const int* fpD = flags + (60 + b * 4 + 3) * 32;
  int s0 = 0, s1 = 0, sA = 0, sB = 0, sC = 0, sD = 0;

  // prologue: fetch chunk 0 into pcur4, chunk 1 into pnext4
  if (isL0) { spin_until(f0, 8, s0); }  else { spin_until(fpA, 8, sA); }
  uint4 pcur4 = pin4[tid];
  if (isL0) { spin_until(f0, 16, s0); } else { spin_until(fpB, 16, sB); }
  uint4 pnext4 = pin4[512 + tid];

  // group gi: rows 4gi..4gi+2 from wj[3gi..3gi+2], row 4gi+3 from LDS slots 4gi+q.
  // Reduce the 4 rows pairwise so lane lam ends owning row (lam) of its slice.
#define ROW16(acc, WR)                                              \
    acc = dot2(WR[0],  hv0.x, acc); acc = dot2(WR[1],  hv0.y, acc); \
    acc = dot2(WR[2],  hv0.z, acc); acc = dot2(WR[3],  hv0.w, acc); \
    acc = dot2(WR[4],  hv1.x, acc); acc = dot2(WR[5],  hv1.y, acc); \
    acc = dot2(WR[6],  hv1.z, acc); acc = dot2(WR[7],  hv1.w, acc); \
    acc = dot2(WR[8],  hv2.x, acc); acc = dot2(WR[9],  hv2.y, acc); \
    acc = dot2(WR[10], hv2.z, acc); acc = dot2(WR[11], hv2.w, acc); \
    acc = dot2(WR[12], hv3.x, acc); acc = dot2(WR[13], hv3.y, acc); \
    acc = dot2(WR[14], hv3.z, acc); acc = dot2(WR[15], hv3.w, acc)

#define GROUP(gi, OUT)                                               \
  {                                                                  \
    const uint4 wvA = WLw4[(4*gi + 0) * 512 + tid];                  \
    const uint4 wvB = WLw4[(4*gi + 1) * 512 + tid];                  \
    float a0 = 0.f, a1 = 0.f, a2 = 0.f, a3 = 0.f;                    \
    ROW16(a0, wj[3*gi+0]);                                           \
    a3 = dot2(wvA.x, hv0.x, a3); a3 = dot2(wvA.y, hv0.y, a3);        \
    a3 = dot2(wvA.z, hv0.z, a3); a3 = dot2(wvA.w, hv0.w, a3);        \
    const uint4 wvC = WLw4[(4*gi + 2) * 512 + tid];                  \
    const uint4 wvD = WLw4[(4*gi + 3) * 512 + tid];                  \
    ROW16(a1, wj[3*gi+1]);                                           \
    a3 = dot2(wvB.x, hv1.x, a3); a3 = dot2(wvB.y, hv1.y, a3);        \
    a3 = dot2(wvB.z, hv1.z, a3); a3 = dot2(wvB.w, hv1.w, a3);        \
    ROW16(a2, wj[3*gi+2]);                                           \
    a3 = dot2(wvC.x, hv2.x, a3); a3 = dot2(wvC.y, hv2.y, a3);        \
    a3 = dot2(wvC.z, hv2.z, a3); a3 = dot2(wvC.w, hv2.w, a3);        \
    a3 = dot2(wvD.x, hv3.x, a3); a3 = dot2(wvD.y, hv3.y, a3);        \
    a3 = dot2(wvD.z, hv3.z, a3); a3 = dot2(wvD.w, hv3.w, a3);        \
    float t0 = dpp_add<0xB1>(a0), t1 = dpp_add<0xB1>(a1);            \
    float t2 = dpp_add<0xB1>(a2), t3 = dpp_add<0xB1>(a3);            \
    float u0 = b0 ? t1 : t0, u1 = b0 ? t3 : t2;                      \
    u0 = dpp_add<0x4E>(u0); u1 = dpp_add<0x4E>(u1);                  \
    OUT = b1 ? u1 : u0;                                              \
  }

  float hlast = 0.f;
#pragma unroll 1
  for (int c = 0; c < TSEQ / 8; c++) {
#pragma unroll 1
    for (int q = 0; q < 8; q++) {
      const int t = c * 8 + q;
      const int rbase = (t & 1) << 10;   // read buffer
      const int wbase = rbase ^ 1024;    // write buffer

      const uint4 hv0 = *(const uint4*)(hxc + rbase + hadr[0]);
      const uint4 hv1 = *(const uint4*)(hxc + rbase + hadr[1]);
      const uint4 hv2 = *(const uint4*)(hxc + rbase + hadr[2]);
      const uint4 hv3 = *(const uint4*)(hxc + rbase + hadr[3]);

      float G0, G1, G2, G3;
      GROUP(0, G0); GROUP(1, G1); GROUP(2, G2); GROUP(3, G3);
      G0 = dpp_add<0x124>(G0); G1 = dpp_add<0x124>(G1);
      G2 = dpp_add<0x124>(G2); G3 = dpp_add<0x124>(G3);
      float r0 = b2 ? G1 : G0, r1 = b2 ? G3 : G2;
      r0 = dpp_add<0x128>(r0); r1 = dpp_add<0x128>(r1);
      const float red = b3 ? r1 : r0;

      // extract pre-activation q from pcur4 (selects only, no array indexing)
      const u32 wlo  = (q & 4) ? pcur4.z : pcur4.x;
      const u32 whi  = (q & 4) ? pcur4.w : pcur4.y;
      const u32 wsel = (q & 2) ? whi : wlo;
      const u16 pq   = (u16)((q & 1) ? (wsel >> 16) : (wsel & 0xffffu));

      const float h = fast_tanh(red + bias + (float)__builtin_bit_cast(_Float16, pq));
      hlast = h;
      const u16 h16 = __builtin_bit_cast(u16, (_Float16)h);
      *(u16*)(hxc + wbase + waddr) = h16;

      if (isL0) {
        // pack (h[2k], h[2k+1]) via DPP xor1 and store from even lanes
        u32 v = (u32)h16;
        u32 nb = dpp_mov_u32<0xB1>(v);
        if (!(tid & 1)) o0p[(size_t)t * 256 + (tid >> 1)] = v | (nb << 16);
      }

      if (q == 7) __syncthreads();  // full drain (vm for flag release)
      else        lds_barrier();    // LDS-only ordering; vm ops stay in flight
    }

    if (isL0 && tid == 0) rel(flagOut0, c * 8 + 8);

    // rotate chunk buffers, prefetch chunk c+2
    pcur4 = pnext4;
    if (c < TSEQ / 8 - 2) {
      const int c2 = c + 2;
      const int need = 8 * (c2 + 1);
      if (isL0) {
        if (c2 < 128) { spin_until(f0, need, s0); }
        else          { spin_until(f1, need - 1024, s1); }
      } else {
        const int w = c2 & 3;
        if      (w == 0) { spin_until(fpA, need, sA); }
        else if (w == 1) { spin_until(fpB, need, sB); }
        else if (w == 2) { spin_until(fpC, need, sC); }
        else             { spin_until(fpD, need, sD); }
      }
      pnext4 = pin4[(size_t)c2 * 512 + tid];
    }
  }
#undef GROUP
#undef ROW16

  if (!isL0) h1f[(size_t)b * NH + tid] = hlast;
}

__global__ void fc_kernel(const float* __restrict__ h1f, const float* __restrict__ Wfc,
                          const float* __restrict__ bfc, float* __restrict__ out) {
  const int b = blockIdx.x, o = threadIdx.x;  // 20 blocks x 128 threads
  __shared__ float hs[NH];
  for (int i = o; i < NH; i += NOUT) hs[i] = h1f[(size_t)b * NH + i];
  __syncthreads();
  const float4* w4 = (const float4*)(Wfc + (size_t)o * NH);
  const float4* h4 = (const float4*)hs;
  float acc = bfc[o];
#pragma unroll 8
  for (int j = 0; j < NH / 4; j++) {
    float4 w = w4[j], h = h4[j];
    acc += w.x * h.x + w.y * h.y + w.z * h.z + w.w * h.w;
  }
  out[(size_t)b * NOUT + o] = acc;
}

extern "C" void kernel_launch(void* const* d_in, const int* in_sizes, int n_in,
                              void* d_out, int out_size, void* d_ws, size_t ws_size,
                              hipStream_t stream) {
  const float* x    = (const float*)d_in[0];
  const float* h0   = (const float*)d_in[1];
  const float* Wih0 = (const float*)d_in[2];
  const float* Whh0 = (const float*)d_in[3];
  const float* bih0 = (const float*)d_in[4];
  const float* bhh0 = (const float*)d_in[5];
  const float* Wih1 = (const float*)d_in[6];
  const float* Whh1 = (const float*)d_in[7];
  const float* bih1 = (const float*)d_in[8];
  const float* bhh1 = (const float*)d_in[9];
  const float* Wfc  = (const float*)d_in[10];
  const float* bfc  = (const float*)d_in[11];
  float* out = (float*)d_out;

  char* ws = (char*)d_ws;
  size_t off = 0;
  u16* pre0 = (u16*)(ws + off); off += (size_t)NB * TSEQ * NH * 2;
  u32* out0 = (u32*)(ws + off); off += (size_t)NB * TSEQ * (NH / 2) * 4;
  u16* pre1 = (u16*)(ws + off); off += (size_t)NB * TSEQ * NH * 2;
  float* h1f = (float*)(ws + off); off += (size_t)NB * NH * 4;
  int* flags = (int*)(ws + off);
  const size_t flagbytes = 160 * 32 * sizeof(int);

  hipMemsetAsync(flags, 0, flagbytes, stream);
  hipFuncSetAttribute((const void*)rnn_persist,
                      hipFuncAttributeMaxDynamicSharedMemorySize, SMEM_BYTES);
  rnn_persist<<<160, 512, SMEM_BYTES, stream>>>(
      x, h0, Wih0, Whh0, bih0, bhh0, Wih1, Whh1, bih1, bhh1,
      pre0, out0, pre1, h1f, flags);
  fc_kernel<<<NB, NOUT, 0, stream>>>(h1f, Wfc, bfc, out);
}